// Round 2
// baseline (71500.995 us; speedup 1.0000x reference)
//
#include <hip/hip_runtime.h>

typedef unsigned int   uint;
typedef unsigned short ushort;

#define NINP    512
#define NHID    1024
#define T_STEPS 512
#define B_SZ    64
#define KTOT    1536                 // NINP + NHID (fused K)
#define BN      (B_SZ * NHID)        // 65536

typedef __attribute__((ext_vector_type(8))) short bf16x8;
typedef __attribute__((ext_vector_type(4))) float f32x4;

// ---------------- ws layout (bytes) ----------------
// wcomb bf16 [3][1024][1536] : gate-major, k<512 = Wi, k>=512 = Wh
#define WCOMB_BYTES (3 * NHID * KTOT * 2)            // 9,437,184
#define WS_BSUM     (WCOMB_BYTES)                    // f32 [3][1024]
#define WS_HHI      (WS_BSUM + 3 * NHID * 4)         // bf16 [64][1024]
#define WS_HLO      (WS_HHI + BN * 2)
#define WS_RHHI     (WS_HLO + BN * 2)
#define WS_RHLO     (WS_RHHI + BN * 2)
#define WS_BAR      (WS_RHLO + BN * 2)               // uint[512]
#define WS_NEED     (WS_BAR + 2048)                  // ~9.52 MB (ws >= 4.72 MB known)

#define SUP_IDX 256
#define GEN_IDX 288

__device__ __forceinline__ float sigmoidf_(float x) { return 1.0f / (1.0f + __expf(-x)); }
__device__ __forceinline__ float tanhf_(float x)    { return 1.0f - 2.0f / (__expf(2.0f * x) + 1.0f); }

__device__ __forceinline__ ushort bf16_rne(float f) {
    uint u = __float_as_uint(f);
    return (ushort)((u + 0x7FFFu + ((u >> 16) & 1u)) >> 16);
}
__device__ __forceinline__ float bf16_to_f(ushort s) {
    return __uint_as_float(((uint)s) << 16);
}
__device__ __forceinline__ bf16x8 ld8(const ushort* p) { return *(const bf16x8*)p; }
__device__ __forceinline__ bf16x8 cvt8(const float* p) {
    float4 a = *(const float4*)p;
    float4 b = *(const float4*)(p + 4);
    bf16x8 r;
    r[0] = (short)bf16_rne(a.x); r[1] = (short)bf16_rne(a.y);
    r[2] = (short)bf16_rne(a.z); r[3] = (short)bf16_rne(a.w);
    r[4] = (short)bf16_rne(b.x); r[5] = (short)bf16_rne(b.y);
    r[6] = (short)bf16_rne(b.z); r[7] = (short)bf16_rne(b.w);
    return r;
}
#define MFMA(a, b, c) __builtin_amdgcn_mfma_f32_16x16x32_bf16((a), (b), (c), 0, 0, 0)

// ---------------- prep: weights -> fused bf16 layout ----------------
__global__ __launch_bounds__(256) void prep_w(
    const float* __restrict__ Wiz, const float* __restrict__ Wir, const float* __restrict__ Wih,
    const float* __restrict__ Whz, const float* __restrict__ Whr, const float* __restrict__ Whh,
    ushort* __restrict__ wcomb)
{
    int tid = blockIdx.x * 256 + threadIdx.x;        // 0 .. 589823
    int oct = tid % (KTOT / 8);                      // 0..191
    int row = tid / (KTOT / 8);                      // gate*1024 + n
    int gate = row >> 10, n = row & 1023;
    int k0 = oct * 8;
    const float* src; int off;
    if (k0 < NINP) { src = gate == 0 ? Wiz : (gate == 1 ? Wir : Wih); off = n * NINP + k0; }
    else           { src = gate == 0 ? Whz : (gate == 1 ? Whr : Whh); off = n * NHID + (k0 - NINP); }
    ushort* dst = wcomb + (size_t)row * KTOT + k0;
    #pragma unroll
    for (int j = 0; j < 8; ++j) dst[j] = bf16_rne(src[off + j]);
}

// ---------------- prep: h0 hi/lo, bias sums, barrier zero ----------------
__global__ __launch_bounds__(256) void prep_misc(
    const float* __restrict__ h0,
    const float* __restrict__ biz, const float* __restrict__ bir, const float* __restrict__ bih,
    const float* __restrict__ bhz, const float* __restrict__ bhr, const float* __restrict__ bhh,
    ushort* __restrict__ hhi, ushort* __restrict__ hlo, float* __restrict__ bsum,
    uint* __restrict__ bar)
{
    if (blockIdx.x < 256) {
        int i = blockIdx.x * 256 + threadIdx.x;      // 0..65535
        float v = h0[i];
        ushort hi = bf16_rne(v);
        ushort lo = bf16_rne(v - bf16_to_f(hi));
        hhi[i] = hi; hlo[i] = lo;
    } else {
        for (int n = threadIdx.x; n < NHID; n += 256) {
            bsum[n]            = biz[n] + bhz[n];
            bsum[NHID + n]     = bir[n] + bhr[n];
            bsum[2 * NHID + n] = bih[n] + bhh[n];
        }
        for (int i = threadIdx.x; i < 512; i += 256) bar[i] = 0u;
    }
}

// ---------------- two-level grid barrier (256 blocks, 8 groups of 32) ----------------
__device__ __forceinline__ void grid_barrier(uint* bar) {
    __threadfence();
    __syncthreads();
    if (threadIdx.x == 0) {
        uint g = __hip_atomic_load(&bar[GEN_IDX], __ATOMIC_RELAXED, __HIP_MEMORY_SCOPE_AGENT);
        int grp = blockIdx.x >> 5;
        uint a = __hip_atomic_fetch_add(&bar[grp * 32], 1u, __ATOMIC_ACQ_REL, __HIP_MEMORY_SCOPE_AGENT);
        if (a == 31u) {
            uint s = __hip_atomic_fetch_add(&bar[SUP_IDX], 1u, __ATOMIC_ACQ_REL, __HIP_MEMORY_SCOPE_AGENT);
            if (s == 7u) {
                #pragma unroll
                for (int i = 0; i < 8; ++i)
                    __hip_atomic_store(&bar[i * 32], 0u, __ATOMIC_RELAXED, __HIP_MEMORY_SCOPE_AGENT);
                __hip_atomic_store(&bar[SUP_IDX], 0u, __ATOMIC_RELAXED, __HIP_MEMORY_SCOPE_AGENT);
                __hip_atomic_store(&bar[GEN_IDX], g + 1u, __ATOMIC_RELEASE, __HIP_MEMORY_SCOPE_AGENT);
            }
        }
        while (__hip_atomic_load(&bar[GEN_IDX], __ATOMIC_ACQUIRE, __HIP_MEMORY_SCOPE_AGENT) == g)
            __builtin_amdgcn_s_sleep(2);
    }
    __syncthreads();
    __threadfence();
}

// ---------------- persistent GRU ----------------
// block(mt = blk&3, nt = blk>>2): batch tile mt (16 b) x gate-row tile nt (16 n).
// wave roles per step:
//   phase1: w0 z(h_hi), w1 r(h_hi), w2 z(x + h_lo), w3 r(x + h_lo); combine via LDS
//           w0 keeps sigmoid(z) in regs; w1 writes rh hi/lo bf16 to ws
//   phase2: w0 c(rh_hi), w1 c(x + rh_lo); combine; w0 epilogue -> out fp32, h hi/lo
__global__ __launch_bounds__(256) void gru_persist(
    const float* __restrict__ x, const float* __restrict__ h0,
    const void* __restrict__ lengths_raw,
    const ushort* __restrict__ wcomb, const float* __restrict__ bsum,
    ushort* __restrict__ hhi, ushort* __restrict__ hlo,
    ushort* __restrict__ rhhi, ushort* __restrict__ rhlo,
    uint* __restrict__ bar, float* __restrict__ out)
{
    const int blk = blockIdx.x;
    const int mt = blk & 3, nt = blk >> 2;
    const int bbase = mt * 16, nbase = nt * 16;
    const int tid = threadIdx.x;
    const int wv = tid >> 6, lane = tid & 63;
    const int col = lane & 15, quad = lane >> 4;

    __shared__ float  lds_h[16 * 17];       // h tile fp32, [b_local][n_local], stride 17
    __shared__ f32x4  lds_p[3][64];         // partial accs: z, r, c

    {   // init h tile from h0
        int bl = tid >> 4, nl = tid & 15;
        lds_h[bl * 17 + nl] = h0[(size_t)(bbase + bl) * NHID + nbase + nl];
    }

    // lengths: int64 per reference, int32 if JAX x64 off. lengths[0]==512 always.
    const int* l32 = (const int*)lengths_raw;
    const bool is64 = (l32[1] == 0);
    int len[4];
    #pragma unroll
    for (int i = 0; i < 4; ++i) {
        int b = bbase + quad * 4 + i;
        len[i] = is64 ? (int)((const long long*)lengths_raw)[b] : l32[b];
    }

    const int q8 = quad * 8;
    const ushort* wz = wcomb + (size_t)(0 * NHID + nbase + col) * KTOT + q8;
    const ushort* wr = wcomb + (size_t)(1 * NHID + nbase + col) * KTOT + q8;
    const ushort* wc = wcomb + (size_t)(2 * NHID + nbase + col) * KTOT + q8;
    const ushort* ha_hi  = hhi  + (size_t)(bbase + col) * NHID + q8;
    const ushort* ha_lo  = hlo  + (size_t)(bbase + col) * NHID + q8;
    const ushort* rha_hi = rhhi + (size_t)(bbase + col) * NHID + q8;
    const ushort* rha_lo = rhlo + (size_t)(bbase + col) * NHID + q8;
    const float*  xrow0  = x + (size_t)(bbase + col) * NINP + q8;

    const float bias_z = bsum[nbase + col];
    const float bias_r = bsum[NHID + nbase + col];
    const float bias_c = bsum[2 * NHID + nbase + col];

    f32x4 zsig = {0, 0, 0, 0};
    __syncthreads();

    for (int t = 0; t < T_STEPS; ++t) {
        const float* xr = xrow0 + (size_t)t * B_SZ * NINP;

        // ---------------- phase 1: z, r ----------------
        {
            f32x4 acc = {0, 0, 0, 0};
            if (wv == 0) {
                acc[0] = acc[1] = acc[2] = acc[3] = bias_z;
                #pragma unroll 4
                for (int ks = 0; ks < 32; ++ks)
                    acc = MFMA(ld8(ha_hi + ks * 32), ld8(wz + NINP + ks * 32), acc);
            } else if (wv == 1) {
                acc[0] = acc[1] = acc[2] = acc[3] = bias_r;
                #pragma unroll 4
                for (int ks = 0; ks < 32; ++ks)
                    acc = MFMA(ld8(ha_hi + ks * 32), ld8(wr + NINP + ks * 32), acc);
            } else if (wv == 2) {
                #pragma unroll 4
                for (int ks = 0; ks < 16; ++ks)
                    acc = MFMA(cvt8(xr + ks * 32), ld8(wz + ks * 32), acc);
                #pragma unroll 4
                for (int ks = 0; ks < 32; ++ks)
                    acc = MFMA(ld8(ha_lo + ks * 32), ld8(wz + NINP + ks * 32), acc);
            } else {
                #pragma unroll 4
                for (int ks = 0; ks < 16; ++ks)
                    acc = MFMA(cvt8(xr + ks * 32), ld8(wr + ks * 32), acc);
                #pragma unroll 4
                for (int ks = 0; ks < 32; ++ks)
                    acc = MFMA(ld8(ha_lo + ks * 32), ld8(wr + NINP + ks * 32), acc);
            }
            if (wv >= 2) lds_p[wv - 2][lane] = acc;
            __syncthreads();
            if (wv == 0) {
                f32x4 p = lds_p[0][lane];
                #pragma unroll
                for (int i = 0; i < 4; ++i) zsig[i] = sigmoidf_(acc[i] + p[i]);
            } else if (wv == 1) {
                f32x4 p = lds_p[1][lane];
                #pragma unroll
                for (int i = 0; i < 4; ++i) {
                    float r  = sigmoidf_(acc[i] + p[i]);
                    float h  = lds_h[(quad * 4 + i) * 17 + col];
                    float rh = r * h;
                    ushort hi16 = bf16_rne(rh);
                    ushort lo16 = bf16_rne(rh - bf16_to_f(hi16));
                    size_t idx = (size_t)(bbase + quad * 4 + i) * NHID + nbase + col;
                    rhhi[idx] = hi16; rhlo[idx] = lo16;
                }
            }
        }
        grid_barrier(bar);   // A: rh visible everywhere

        // ---------------- phase 2: c, h update ----------------
        {
            f32x4 acc = {0, 0, 0, 0};
            if (wv == 0) {
                acc[0] = acc[1] = acc[2] = acc[3] = bias_c;
                #pragma unroll 4
                for (int ks = 0; ks < 32; ++ks)
                    acc = MFMA(ld8(rha_hi + ks * 32), ld8(wc + NINP + ks * 32), acc);
            } else if (wv == 1) {
                #pragma unroll 4
                for (int ks = 0; ks < 16; ++ks)
                    acc = MFMA(cvt8(xr + ks * 32), ld8(wc + ks * 32), acc);
                #pragma unroll 4
                for (int ks = 0; ks < 32; ++ks)
                    acc = MFMA(ld8(rha_lo + ks * 32), ld8(wc + NINP + ks * 32), acc);
                lds_p[2][lane] = acc;
            }
            __syncthreads();
            if (wv == 0) {
                f32x4 p = lds_p[2][lane];
                float* out_t = out + (size_t)t * BN;
                #pragma unroll
                for (int i = 0; i < 4; ++i) {
                    float c = tanhf_(acc[i] + p[i]);
                    int bl = quad * 4 + i;
                    float h = lds_h[bl * 17 + col];
                    float z = zsig[i];
                    float hn = (t < len[i]) ? fmaf(z, c - h, h) : h;
                    size_t idx = (size_t)(bbase + bl) * NHID + nbase + col;
                    out_t[idx] = hn;
                    if (t == T_STEPS - 1) out[(size_t)T_STEPS * BN + idx] = hn;
                    lds_h[bl * 17 + col] = hn;
                    ushort hi16 = bf16_rne(hn);
                    ushort lo16 = bf16_rne(hn - bf16_to_f(hi16));
                    hhi[idx] = hi16; hlo[idx] = lo16;
                }
            }
        }
        grid_barrier(bar);   // B: h hi/lo visible everywhere
    }
}

// ws_size probe: no-op; gridDim.x = ws_size_in_MB + 1 (read from rocprof dispatch dims).
__global__ void gru_ws_probe_mb(float* p) {
    if (blockIdx.x == 0xFFFFFFFFu) p[0] = 0.f;
}

extern "C" void kernel_launch(void* const* d_in, const int* in_sizes, int n_in,
                              void* d_out, int out_size, void* d_ws, size_t ws_size,
                              hipStream_t stream) {
    const float* x   = (const float*)d_in[0];
    const float* h0  = (const float*)d_in[1];
    const float* Wiz = (const float*)d_in[2];  const float* biz = (const float*)d_in[3];
    const float* Wir = (const float*)d_in[4];  const float* bir = (const float*)d_in[5];
    const float* Wih = (const float*)d_in[6];  const float* bih = (const float*)d_in[7];
    const float* Whz = (const float*)d_in[8];  const float* bhz = (const float*)d_in[9];
    const float* Whr = (const float*)d_in[10]; const float* bhr = (const float*)d_in[11];
    const float* Whh = (const float*)d_in[12]; const float* bhh = (const float*)d_in[13];
    const void*  lengths = d_in[14];
    float* out = (float*)d_out;
    char*  ws  = (char*)d_ws;

    size_t mb = ws_size >> 20; if (mb > 2048) mb = 2048;
    gru_ws_probe_mb<<<dim3((uint)mb + 1), 64, 0, stream>>>((float*)d_ws);
    if (ws_size < (size_t)WS_NEED) return;   // bench will fail loudly; probe reports ws

    ushort* wcomb = (ushort*)ws;
    float*  bsum  = (float*)(ws + WS_BSUM);
    ushort* hhi   = (ushort*)(ws + WS_HHI);
    ushort* hlo   = (ushort*)(ws + WS_HLO);
    ushort* rhhi  = (ushort*)(ws + WS_RHHI);
    ushort* rhlo  = (ushort*)(ws + WS_RHLO);
    uint*   bar   = (uint*)(ws + WS_BAR);

    prep_w<<<2304, 256, 0, stream>>>(Wiz, Wir, Wih, Whz, Whr, Whh, wcomb);
    prep_misc<<<257, 256, 0, stream>>>(h0, biz, bir, bih, bhz, bhr, bhh, hhi, hlo, bsum, bar);
    gru_persist<<<256, 256, 0, stream>>>(x, h0, lengths, wcomb, bsum,
                                         hhi, hlo, rhhi, rhlo, bar, out);
}

// Round 3
// 27386.963 us; speedup vs baseline: 2.6108x; 2.6108x over previous
//
#include <hip/hip_runtime.h>

typedef unsigned int   uint;
typedef unsigned short ushort;

#define NINP    512
#define NHID    1024
#define T_STEPS 512
#define B_SZ    64
#define KTOT    1536                 // NINP + NHID fused K
#define BN      (B_SZ * NHID)        // 65536

typedef __attribute__((ext_vector_type(8))) short bf16x8;
typedef __attribute__((ext_vector_type(4))) float f32x4;

// ---------------- ws layout (bytes) ----------------
#define WCOMB_BYTES (3 * NHID * KTOT * 2)            // 9,437,184
#define WS_BSUM     (WCOMB_BYTES)                    // f32 [3][1024]
#define WS_HHI      (WS_BSUM + 3 * NHID * 4)         // bf16 [64][1024]
#define WS_HLO      (WS_HHI + BN * 2)
#define WS_RHHI     (WS_HLO + BN * 2)
#define WS_RHLO     (WS_RHHI + BN * 2)
#define WS_BAR      (WS_RHLO + BN * 2)               // uint[512]
#define WS_NEED     (WS_BAR + 2048)                  // ~9.52 MB (ws >= this: ran in R2)

#define SUP_IDX 256
#define GEN_IDX 288

__device__ __forceinline__ float sigmoidf_(float x) { return 1.0f / (1.0f + __expf(-x)); }
__device__ __forceinline__ float tanhf_(float x)    { return 1.0f - 2.0f / (__expf(2.0f * x) + 1.0f); }

__device__ __forceinline__ ushort bf16_rne(float f) {
    uint u = __float_as_uint(f);
    return (ushort)((u + 0x7FFFu + ((u >> 16) & 1u)) >> 16);
}
__device__ __forceinline__ float bf16_to_f(ushort s) { return __uint_as_float(((uint)s) << 16); }
__device__ __forceinline__ bf16x8 ld8(const ushort* p) { return *(const bf16x8*)p; }
__device__ __forceinline__ bf16x8 cvt8(const float* p) {
    float4 a = *(const float4*)p;
    float4 b = *(const float4*)(p + 4);
    bf16x8 r;
    r[0] = (short)bf16_rne(a.x); r[1] = (short)bf16_rne(a.y);
    r[2] = (short)bf16_rne(a.z); r[3] = (short)bf16_rne(a.w);
    r[4] = (short)bf16_rne(b.x); r[5] = (short)bf16_rne(b.y);
    r[6] = (short)bf16_rne(b.z); r[7] = (short)bf16_rne(b.w);
    return r;
}
#define MFMA(a, b, c) __builtin_amdgcn_mfma_f32_16x16x32_bf16((a), (b), (c), 0, 0, 0)

// ---------------- prep: weights -> fused bf16 layout ----------------
__global__ __launch_bounds__(256) void prep_w(
    const float* __restrict__ Wiz, const float* __restrict__ Wir, const float* __restrict__ Wih,
    const float* __restrict__ Whz, const float* __restrict__ Whr, const float* __restrict__ Whh,
    ushort* __restrict__ wcomb)
{
    int tid = blockIdx.x * 256 + threadIdx.x;
    int oct = tid % (KTOT / 8);
    int row = tid / (KTOT / 8);                      // gate*1024 + n
    int gate = row >> 10, n = row & 1023;
    int k0 = oct * 8;
    const float* src; int off;
    if (k0 < NINP) { src = gate == 0 ? Wiz : (gate == 1 ? Wir : Wih); off = n * NINP + k0; }
    else           { src = gate == 0 ? Whz : (gate == 1 ? Whr : Whh); off = n * NHID + (k0 - NINP); }
    ushort* dst = wcomb + (size_t)row * KTOT + k0;
    #pragma unroll
    for (int j = 0; j < 8; ++j) dst[j] = bf16_rne(src[off + j]);
}

// ---------------- prep: h0 hi/lo, bias sums, barrier zero ----------------
__global__ __launch_bounds__(256) void prep_misc(
    const float* __restrict__ h0,
    const float* __restrict__ biz, const float* __restrict__ bir, const float* __restrict__ bih,
    const float* __restrict__ bhz, const float* __restrict__ bhr, const float* __restrict__ bhh,
    ushort* __restrict__ hhi, ushort* __restrict__ hlo, float* __restrict__ bsum,
    uint* __restrict__ bar)
{
    if (blockIdx.x < 256) {
        int i = blockIdx.x * 256 + threadIdx.x;
        float v = h0[i];
        ushort hi = bf16_rne(v);
        ushort lo = bf16_rne(v - bf16_to_f(hi));
        hhi[i] = hi; hlo[i] = lo;
    } else {
        for (int n = threadIdx.x; n < NHID; n += 256) {
            bsum[n]            = biz[n] + bhz[n];
            bsum[NHID + n]     = bir[n] + bhr[n];
            bsum[2 * NHID + n] = bih[n] + bhh[n];
        }
        for (int i = threadIdx.x; i < 512; i += 256) bar[i] = 0u;
    }
}

// ---------------- grid barrier: 64 blocks, 8 groups x 8, relaxed arrivals ----------------
__device__ __forceinline__ void grid_barrier(uint* bar) {
    __builtin_amdgcn_fence(__ATOMIC_RELEASE, "agent");   // push this thread's stores to L3
    __syncthreads();
    if (threadIdx.x == 0) {
        uint g = __hip_atomic_load(&bar[GEN_IDX], __ATOMIC_RELAXED, __HIP_MEMORY_SCOPE_AGENT);
        int grp = blockIdx.x >> 3;
        uint a = __hip_atomic_fetch_add(&bar[grp * 32], 1u, __ATOMIC_RELAXED, __HIP_MEMORY_SCOPE_AGENT);
        if (a == 7u) {
            uint s = __hip_atomic_fetch_add(&bar[SUP_IDX], 1u, __ATOMIC_RELAXED, __HIP_MEMORY_SCOPE_AGENT);
            if (s == 7u) {
                #pragma unroll
                for (int i = 0; i < 8; ++i)
                    __hip_atomic_store(&bar[i * 32], 0u, __ATOMIC_RELAXED, __HIP_MEMORY_SCOPE_AGENT);
                __hip_atomic_store(&bar[SUP_IDX], 0u, __ATOMIC_RELAXED, __HIP_MEMORY_SCOPE_AGENT);
                __hip_atomic_store(&bar[GEN_IDX], g + 1u, __ATOMIC_RELEASE, __HIP_MEMORY_SCOPE_AGENT);
            }
        }
        while (__hip_atomic_load(&bar[GEN_IDX], __ATOMIC_RELAXED, __HIP_MEMORY_SCOPE_AGENT) == g)
            __builtin_amdgcn_s_sleep(1);
    }
    __syncthreads();
    __builtin_amdgcn_fence(__ATOMIC_ACQUIRE, "agent");   // invalidate stale cache lines
}

// ---------------- persistent GRU: 64 blocks, weights in VGPRs ----------------
// Block nt owns n-cols [nt*16, nt*16+16) for all 3 gates, all 64 batch rows.
// Wave w: K-steps j = w + 4s (s=0..11) over fused K=1536 (j<16: x, else h hi+lo).
// Epilogue: wave w reduces + updates M-tile w (batch rows [w*16, w*16+16)).
__global__ __launch_bounds__(256, 1) void gru_persist(
    const float* __restrict__ x, const float* __restrict__ h0,
    const void* __restrict__ lengths_raw,
    const ushort* __restrict__ wcomb, const float* __restrict__ bsum,
    ushort* __restrict__ hhi, ushort* __restrict__ hlo,
    ushort* __restrict__ rhhi, ushort* __restrict__ rhlo,
    uint* __restrict__ bar, float* __restrict__ out)
{
    const int nbase = blockIdx.x * 16;
    const int tid = threadIdx.x;
    const int wv = tid >> 6, lane = tid & 63;
    const int col = lane & 15, quad = lane >> 4;
    const int q8 = quad * 8;

    __shared__ f32x4 lds_acc[4][2][4][64];   // [wave][gate][mtile][lane]  32 KB
    __shared__ float lds_h[64 * 17];         // h fp32 [b][n_local], pad 17  4.4 KB

    for (int idx = tid; idx < 1024; idx += 256)
        lds_h[(idx >> 4) * 17 + (idx & 15)] = h0[(size_t)(idx >> 4) * NHID + nbase + (idx & 15)];

    // ---- weight fragments -> VGPRs (once) ----
    bf16x8 wfz[12], wfr[12], wfc[12];
    #pragma unroll
    for (int s = 0; s < 12; ++s) {
        const int j = wv + 4 * s;            // K-step 0..47
        const size_t ko = (size_t)j * 32 + q8;
        wfz[s] = ld8(wcomb + (size_t)(0 * NHID + nbase + col) * KTOT + ko);
        wfr[s] = ld8(wcomb + (size_t)(1 * NHID + nbase + col) * KTOT + ko);
        wfc[s] = ld8(wcomb + (size_t)(2 * NHID + nbase + col) * KTOT + ko);
    }

    // lengths: int64 per reference, int32 if x64 disabled
    const int* l32 = (const int*)lengths_raw;
    const bool is64 = (l32[1] == 0);
    int len[4];
    #pragma unroll
    for (int i = 0; i < 4; ++i) {
        int b = wv * 16 + quad * 4 + i;
        len[i] = is64 ? (int)((const long long*)lengths_raw)[b] : l32[b];
    }

    const float bias_z = bsum[nbase + col];
    const float bias_r = bsum[NHID + nbase + col];
    const float bias_c = bsum[2 * NHID + nbase + col];

    f32x4 zsig = {0, 0, 0, 0};
    bf16x8 xf[4][4];                         // cached x frags [s][mtile]
    __syncthreads();

    for (int t = 0; t < T_STEPS; ++t) {
        const float* x_t = x + (size_t)t * B_SZ * NINP;

        // ================= phase 1: z, r =================
        {
            f32x4 az[4] = {{0,0,0,0},{0,0,0,0},{0,0,0,0},{0,0,0,0}};
            f32x4 ar[4] = {{0,0,0,0},{0,0,0,0},{0,0,0,0},{0,0,0,0}};
            #pragma unroll
            for (int s = 0; s < 4; ++s) {              // x region (j = wv+4s < 16)
                const int k = (wv + 4 * s) * 32;
                #pragma unroll
                for (int m = 0; m < 4; ++m) {
                    bf16x8 xa = cvt8(x_t + (size_t)(m * 16 + col) * NINP + k + q8);
                    xf[s][m] = xa;
                    az[m] = MFMA(xa, wfz[s], az[m]);
                    ar[m] = MFMA(xa, wfr[s], ar[m]);
                }
            }
            #pragma unroll
            for (int s = 4; s < 12; ++s) {             // h region
                const int kh = (wv + 4 * s) * 32 - NINP;
                #pragma unroll
                for (int m = 0; m < 4; ++m) {
                    const size_t ao = (size_t)(m * 16 + col) * NHID + kh + q8;
                    bf16x8 hi = ld8(hhi + ao);
                    bf16x8 lo = ld8(hlo + ao);
                    az[m] = MFMA(hi, wfz[s], az[m]);
                    ar[m] = MFMA(hi, wfr[s], ar[m]);
                    az[m] = MFMA(lo, wfz[s], az[m]);
                    ar[m] = MFMA(lo, wfr[s], ar[m]);
                }
            }
            #pragma unroll
            for (int m = 0; m < 4; ++m) {
                lds_acc[wv][0][m][lane] = az[m];
                lds_acc[wv][1][m][lane] = ar[m];
            }
            __syncthreads();
            // wave wv reduces M-tile wv
            f32x4 zp = {bias_z, bias_z, bias_z, bias_z};
            f32x4 rp = {bias_r, bias_r, bias_r, bias_r};
            #pragma unroll
            for (int w = 0; w < 4; ++w) {
                f32x4 a = lds_acc[w][0][wv][lane];
                f32x4 b = lds_acc[w][1][wv][lane];
                #pragma unroll
                for (int i = 0; i < 4; ++i) { zp[i] += a[i]; rp[i] += b[i]; }
            }
            #pragma unroll
            for (int i = 0; i < 4; ++i) {
                zsig[i] = sigmoidf_(zp[i]);
                const int bl = wv * 16 + quad * 4 + i;
                const float r  = sigmoidf_(rp[i]);
                const float rh = r * lds_h[bl * 17 + col];
                const ushort hi16 = bf16_rne(rh);
                const ushort lo16 = bf16_rne(rh - bf16_to_f(hi16));
                const size_t gi = (size_t)bl * NHID + nbase + col;
                rhhi[gi] = hi16; rhlo[gi] = lo16;
            }
        }
        grid_barrier(bar);    // A: rh visible device-wide

        // ================= phase 2: c, h update =================
        {
            f32x4 ac[4] = {{0,0,0,0},{0,0,0,0},{0,0,0,0},{0,0,0,0}};
            #pragma unroll
            for (int s = 0; s < 4; ++s)
                #pragma unroll
                for (int m = 0; m < 4; ++m)
                    ac[m] = MFMA(xf[s][m], wfc[s], ac[m]);
            #pragma unroll
            for (int s = 4; s < 12; ++s) {
                const int kh = (wv + 4 * s) * 32 - NINP;
                #pragma unroll
                for (int m = 0; m < 4; ++m) {
                    const size_t ao = (size_t)(m * 16 + col) * NHID + kh + q8;
                    bf16x8 hi = ld8(rhhi + ao);
                    bf16x8 lo = ld8(rhlo + ao);
                    ac[m] = MFMA(hi, wfc[s], ac[m]);
                    ac[m] = MFMA(lo, wfc[s], ac[m]);
                }
            }
            #pragma unroll
            for (int m = 0; m < 4; ++m) lds_acc[wv][0][m][lane] = ac[m];
            __syncthreads();
            f32x4 cp = {bias_c, bias_c, bias_c, bias_c};
            #pragma unroll
            for (int w = 0; w < 4; ++w) {
                f32x4 a = lds_acc[w][0][wv][lane];
                #pragma unroll
                for (int i = 0; i < 4; ++i) cp[i] += a[i];
            }
            float* out_t = out + (size_t)t * BN;
            #pragma unroll
            for (int i = 0; i < 4; ++i) {
                const int bl = wv * 16 + quad * 4 + i;
                const float c = tanhf_(cp[i]);
                const float h = lds_h[bl * 17 + col];
                const float hn = (t < len[i]) ? fmaf(zsig[i], c - h, h) : h;
                const size_t gi = (size_t)bl * NHID + nbase + col;
                out_t[gi] = hn;
                if (t == T_STEPS - 1) out[(size_t)T_STEPS * BN + gi] = hn;
                lds_h[bl * 17 + col] = hn;
                const ushort hi16 = bf16_rne(hn);
                const ushort lo16 = bf16_rne(hn - bf16_to_f(hi16));
                hhi[gi] = hi16; hlo[gi] = lo16;
            }
        }
        grid_barrier(bar);    // B: h visible device-wide
    }
}

// ws_size probe: no-op; gridDim.x = ws_size_in_MB + 1 (read from rocprof dims).
__global__ void gru_ws_probe_mb(float* p) {
    if (blockIdx.x == 0xFFFFFFFFu) p[0] = 0.f;
}

extern "C" void kernel_launch(void* const* d_in, const int* in_sizes, int n_in,
                              void* d_out, int out_size, void* d_ws, size_t ws_size,
                              hipStream_t stream) {
    const float* x   = (const float*)d_in[0];
    const float* h0  = (const float*)d_in[1];
    const float* Wiz = (const float*)d_in[2];  const float* biz = (const float*)d_in[3];
    const float* Wir = (const float*)d_in[4];  const float* bir = (const float*)d_in[5];
    const float* Wih = (const float*)d_in[6];  const float* bih = (const float*)d_in[7];
    const float* Whz = (const float*)d_in[8];  const float* bhz = (const float*)d_in[9];
    const float* Whr = (const float*)d_in[10]; const float* bhr = (const float*)d_in[11];
    const float* Whh = (const float*)d_in[12]; const float* bhh = (const float*)d_in[13];
    const void*  lengths = d_in[14];
    float* out = (float*)d_out;
    char*  ws  = (char*)d_ws;

    size_t mb = ws_size >> 20; if (mb > 2048) mb = 2048;
    gru_ws_probe_mb<<<dim3((uint)mb + 1), 64, 0, stream>>>((float*)d_ws);
    if (ws_size < (size_t)WS_NEED) return;

    ushort* wcomb = (ushort*)ws;
    float*  bsum  = (float*)(ws + WS_BSUM);
    ushort* hhi   = (ushort*)(ws + WS_HHI);
    ushort* hlo   = (ushort*)(ws + WS_HLO);
    ushort* rhhi  = (ushort*)(ws + WS_RHHI);
    ushort* rhlo  = (ushort*)(ws + WS_RHLO);
    uint*   bar   = (uint*)(ws + WS_BAR);

    prep_w<<<2304, 256, 0, stream>>>(Wiz, Wir, Wih, Whz, Whr, Whh, wcomb);
    prep_misc<<<257, 256, 0, stream>>>(h0, biz, bir, bih, bhz, bhr, bhh, hhi, hlo, bsum, bar);
    gru_persist<<<64, 256, 0, stream>>>(x, h0, lengths, wcomb, bsum,
                                        hhi, hlo, rhhi, rhlo, bar, out);
}